// Round 5
// baseline (504.305 us; speedup 1.0000x reference)
//
#include <hip/hip_runtime.h>

// ---- problem constants ----
#define B_  4
#define S_  2048
#define H_  1024
#define NH_ 16
#define HD_ 64
#define FF_ 4096
#define M_  (B_*S_)   // 8192 rows

typedef __bf16 bf16x8 __attribute__((ext_vector_type(8)));
typedef float  f32x4  __attribute__((ext_vector_type(4)));
typedef unsigned short ushort8v __attribute__((ext_vector_type(8)));
typedef unsigned short ushort4v __attribute__((ext_vector_type(4)));

typedef __attribute__((address_space(1))) void GVOID;
typedef __attribute__((address_space(3))) void LVOID;

__device__ __forceinline__ void g2l16(const void* g, void* l) {
  __builtin_amdgcn_global_load_lds((GVOID*)g, (LVOID*)l, 16, 0, 0);
}

#if __has_builtin(__builtin_amdgcn_exp2f)
#define EXP2(x) __builtin_amdgcn_exp2f(x)
#else
#define EXP2(x) exp2f(x)
#endif

__device__ __forceinline__ unsigned short f2bf(float f) {
  unsigned int u = __float_as_uint(f);
  u += 0x7fffu + ((u >> 16) & 1u);
  return (unsigned short)(u >> 16);
}
__device__ __forceinline__ float bf2f(unsigned short h) {
  return __uint_as_float(((unsigned int)h) << 16);
}

// bijective XCD swizzle for grids with nwg % 8 == 0
__device__ __forceinline__ void xcd_swz(int& bx, int& by) {
  int gx = gridDim.x;
  int flat = by * gx + bx;
  int cpx = (gx * gridDim.y) >> 3;
  int swz = (flat & 7) * cpx + (flat >> 3);
  bx = swz % gx;
  by = swz / gx;
}

// ---------------- cast fp32 -> bf16 ----------------
__global__ __launch_bounds__(256) void cast_f32_bf16(const float* __restrict__ in,
                                                     unsigned short* __restrict__ out,
                                                     int n4) {
  int i = blockIdx.x * 256 + threadIdx.x;
  if (i >= n4) return;
  float4 v = reinterpret_cast<const float4*>(in)[i];
  ushort4v o;
  o[0] = f2bf(v.x); o[1] = f2bf(v.y); o[2] = f2bf(v.z); o[3] = f2bf(v.w);
  reinterpret_cast<ushort4v*>(out)[i] = o;
}

// ---------------- transpose + cast: W[R][C] f32 -> WT[C][R] bf16 ----------------
__global__ __launch_bounds__(256) void transpose_cast(const float* __restrict__ in,
                                                      unsigned short* __restrict__ out,
                                                      int R, int C) {
  __shared__ float t[32][33];
  const int bx = blockIdx.x * 32;
  const int by = blockIdx.y * 32;
  const int tx = threadIdx.x & 31, ty = threadIdx.x >> 5;
#pragma unroll
  for (int i = 0; i < 32; i += 8)
    t[ty + i][tx] = in[(size_t)(by + ty + i) * C + bx + tx];
  __syncthreads();
#pragma unroll
  for (int i = 0; i < 32; i += 8)
    out[(size_t)(bx + ty + i) * R + by + tx] = f2bf(t[tx][ty + i]);
}

// ======== shared GEMM core: 256x128 tile, BK=32, 8 waves, 2-phase dbuf ========
// wave (tid>>6) owns 64x64 at (wr,wc); staging: 2 A-chunks + 1 B-chunk per wave.
#define GEMM_CORE(A_, Bt_, K_)                                                     \
  __shared__ unsigned short As[2][256 * 32];                                       \
  __shared__ unsigned short Bs[2][128 * 32];                                       \
  const int tid  = threadIdx.x;                                                    \
  const int wave = tid >> 6;                                                       \
  const int lane = tid & 63;                                                       \
  const int kg   = lane >> 4;                                                      \
  const int lr   = lane & 15;                                                      \
  const int wr = (wave >> 1) * 64;                                                 \
  const int wc = (wave & 1) * 64;                                                  \
  const int ra = lane >> 2;                                                        \
  const int ke = ((lane & 3) * 8) ^ (((lane >> 3) & 3) << 3);                      \
  const int swz = ((lr >> 1) & 3) << 3;                                            \
  const unsigned short* pA0 = &A_[(size_t)(m0 + (wave * 2 + 0) * 16 + ra) * K_ + ke]; \
  const unsigned short* pA1 = &A_[(size_t)(m0 + (wave * 2 + 1) * 16 + ra) * K_ + ke]; \
  const unsigned short* pB0 = &Bt_[(size_t)(n0 + wave * 16 + ra) * K_ + ke];       \
  f32x4 acc[4][4] = {};                                                            \
  {                                                                                \
    g2l16(pA0, &As[0][(wave * 2 + 0) * 512]);                                      \
    g2l16(pA1, &As[0][(wave * 2 + 1) * 512]);                                      \
    g2l16(pB0, &Bs[0][wave * 512]);                                                \
  }                                                                                \
  __syncthreads();                                                                 \
  const int nk = (K_) >> 5;                                                        \
  for (int t = 0; t < nk; ++t) {                                                   \
    const int cur = t & 1;                                                         \
    if (t + 1 < nk) {                                                              \
      int k0 = (t + 1) << 5;                                                       \
      g2l16(pA0 + k0, &As[cur ^ 1][(wave * 2 + 0) * 512]);                         \
      g2l16(pA1 + k0, &As[cur ^ 1][(wave * 2 + 1) * 512]);                         \
      g2l16(pB0 + k0, &Bs[cur ^ 1][wave * 512]);                                   \
    }                                                                              \
    bf16x8 af[4], bfr[4];                                                          \
    _Pragma("unroll")                                                              \
    for (int mi = 0; mi < 4; ++mi)                                                 \
      af[mi] = *reinterpret_cast<const bf16x8*>(                                   \
          &As[cur][(wr + mi * 16 + lr) * 32 + ((kg * 8) ^ swz)]);                  \
    _Pragma("unroll")                                                              \
    for (int ni = 0; ni < 4; ++ni)                                                 \
      bfr[ni] = *reinterpret_cast<const bf16x8*>(                                  \
          &Bs[cur][(wc + ni * 16 + lr) * 32 + ((kg * 8) ^ swz)]);                  \
    _Pragma("unroll")                                                              \
    for (int mi = 0; mi < 4; ++mi)                                                 \
      _Pragma("unroll")                                                            \
      for (int ni = 0; ni < 4; ++ni)                                               \
        acc[mi][ni] = __builtin_amdgcn_mfma_f32_16x16x32_bf16(af[mi], bfr[ni],     \
                                                              acc[mi][ni], 0, 0, 0); \
    __syncthreads();                                                               \
  }

// ---------------- generic TN GEMM: C[M,N] = act(A @ Bt^T + bias) ----------------
template<int ACT, int OUT_F32>
__global__ __launch_bounds__(512) void gemm_tn(const unsigned short* __restrict__ A,
                                               const unsigned short* __restrict__ Bt,
                                               const float* __restrict__ bias,
                                               void* __restrict__ C,
                                               int M, int N, int K) {
  int bx = blockIdx.x, by = blockIdx.y;
  xcd_swz(bx, by);
  const int m0 = bx * 256;
  const int n0 = by * 128;
  GEMM_CORE(A, Bt, K)

#pragma unroll
  for (int mi = 0; mi < 4; ++mi) {
#pragma unroll
    for (int ni = 0; ni < 4; ++ni) {
      int col = n0 + wc + ni * 16 + lr;
      float bc = bias[col];
#pragma unroll
      for (int r = 0; r < 4; ++r) {
        int row = m0 + wr + mi * 16 + kg * 4 + r;
        float v = acc[mi][ni][r] + bc;
        if (ACT == 1) v = 0.5f * v * (1.0f + erff(v * 0.70710678118f));
        if (OUT_F32) reinterpret_cast<float*>(C)[(size_t)row * N + col] = v;
        else reinterpret_cast<unsigned short*>(C)[(size_t)row * N + col] = f2bf(v);
      }
    }
  }
}

// ---------------- fused QKV GEMM: N=3072, per-segment epilogue ----------------
// cols [0,1024): Q*QSCALE -> qb ; [1024,2048): K -> kb ; [2048,3072): V -> vt^T
__global__ __launch_bounds__(512) void gemm_qkv(const unsigned short* __restrict__ A,
                                                const unsigned short* __restrict__ Bt,
                                                const float* __restrict__ bq,
                                                const float* __restrict__ bk,
                                                const float* __restrict__ bv,
                                                unsigned short* __restrict__ qb,
                                                unsigned short* __restrict__ kb,
                                                unsigned short* __restrict__ vt,
                                                float qscale) {
  int bx = blockIdx.x, by = blockIdx.y;
  xcd_swz(bx, by);
  const int m0 = bx * 256;
  const int n0 = by * 128;
  GEMM_CORE(A, Bt, H_)

#pragma unroll
  for (int mi = 0; mi < 4; ++mi) {
#pragma unroll
    for (int ni = 0; ni < 4; ++ni) {
      int colb = n0 + wc + ni * 16;        // segment-uniform over the 16 lanes
      int col  = colb + lr;
      int seg  = colb >> 10;               // 0=Q, 1=K, 2=V
      int row0 = m0 + wr + mi * 16 + kg * 4;
      if (seg == 0) {
        float bc = bq[col];
#pragma unroll
        for (int r = 0; r < 4; ++r)
          qb[(size_t)(row0 + r) * H_ + col] = f2bf((acc[mi][ni][r] + bc) * qscale);
      } else if (seg == 1) {
        float bc = bk[col - 1024];
#pragma unroll
        for (int r = 0; r < 4; ++r)
          kb[(size_t)(row0 + r) * H_ + col - 1024] = f2bf(acc[mi][ni][r] + bc);
      } else {
        float bc = bv[col - 2048];
        ushort4v o;
#pragma unroll
        for (int r = 0; r < 4; ++r) o[r] = f2bf(acc[mi][ni][r] + bc);
        *reinterpret_cast<ushort4v*>(&vt[(size_t)(col - 2048) * M_ + row0]) = o;
      }
    }
  }
}

// ---------------- flash attention (unchanged from round 4) ----------------
__global__ __launch_bounds__(256) void attn_fwd(const unsigned short* __restrict__ Q,
                                                const unsigned short* __restrict__ Kb,
                                                const unsigned short* __restrict__ VT,
                                                unsigned short* __restrict__ O) {
  __shared__ unsigned short Ks[2][64 * 64];
  __shared__ unsigned short Vs[2][64 * 64];
  __shared__ __bf16 Ps[4][32 * 40];

  const int tid  = threadIdx.x;
  const int wave = tid >> 6;
  const int lane = tid & 63;
  const int kg   = lane >> 4;
  const int lr   = lane & 15;
  int bx = blockIdx.x, by = blockIdx.y;
  xcd_swz(bx, by);
  const int b  = by >> 4;
  const int h  = by & 15;
  const size_t rowbase = (size_t)b * S_;
  const int hcol = h * 64;
  const int bcol0 = b * S_;
  const int q0 = bx * 128 + wave * 32;

  const int rT0 = (wave * 2 + 0) * 8 + (lane >> 3);
  const int rT1 = (wave * 2 + 1) * 8 + (lane >> 3);
  const int ce  = ((lane & 7) * 8) ^ (((lane >> 3) & 7) << 3);
  const int fswz = (lr & 7) << 3;

  bf16x8 qf[2][2];
#pragma unroll
  for (int sub = 0; sub < 2; ++sub)
#pragma unroll
    for (int d = 0; d < 2; ++d)
      qf[sub][d] = *reinterpret_cast<const bf16x8*>(
          &Q[(rowbase + q0 + sub * 16 + lr) * H_ + hcol + d * 32 + kg * 8]);

  bf16x8 ones;
#pragma unroll
  for (int i = 0; i < 8; ++i) ones[i] = (__bf16)1.0f;

  f32x4 ctx[2][4] = {};
  f32x4 lsum[2] = {};
  float m_w = -1e30f;

  auto stage = [&](int kt, int buf) {
    g2l16(&Kb[(rowbase + kt * 64 + rT0) * H_ + hcol + ce], &Ks[buf][(wave * 2 + 0) * 512]);
    g2l16(&Kb[(rowbase + kt * 64 + rT1) * H_ + hcol + ce], &Ks[buf][(wave * 2 + 1) * 512]);
    g2l16(&VT[(size_t)(hcol + rT0) * M_ + bcol0 + kt * 64 + ce], &Vs[buf][(wave * 2 + 0) * 512]);
    g2l16(&VT[(size_t)(hcol + rT1) * M_ + bcol0 + kt * 64 + ce], &Vs[buf][(wave * 2 + 1) * 512]);
  };

  stage(0, 0);
  __syncthreads();

  const int NT = S_ / 64;
  for (int kt = 0; kt < NT; ++kt) {
    const int cur = kt & 1;
    if (kt + 1 < NT) stage(kt + 1, cur ^ 1);

    f32x4 s0[4], s1[4];
    __builtin_amdgcn_s_setprio(1);
#pragma unroll
    for (int nf = 0; nf < 4; ++nf) {
      int row = nf * 16 + lr;
      bf16x8 kf0 = *reinterpret_cast<const bf16x8*>(&Ks[cur][row * 64 + ((kg * 8) ^ fswz)]);
      bf16x8 kf1 = *reinterpret_cast<const bf16x8*>(&Ks[cur][row * 64 + ((32 + kg * 8) ^ fswz)]);
      f32x4 z0 = {0.f, 0.f, 0.f, 0.f}, z1 = {0.f, 0.f, 0.f, 0.f};
      z0 = __builtin_amdgcn_mfma_f32_16x16x32_bf16(qf[0][0], kf0, z0, 0, 0, 0);
      z0 = __builtin_amdgcn_mfma_f32_16x16x32_bf16(qf[0][1], kf1, z0, 0, 0, 0);
      z1 = __builtin_amdgcn_mfma_f32_16x16x32_bf16(qf[1][0], kf0, z1, 0, 0, 0);
      z1 = __builtin_amdgcn_mfma_f32_16x16x32_bf16(qf[1][1], kf1, z1, 0, 0, 0);
      s0[nf] = z0;
      s1[nf] = z1;
    }
    __builtin_amdgcn_s_setprio(0);

    float mx = -1e30f;
#pragma unroll
    for (int nf = 0; nf < 4; ++nf)
#pragma unroll
      for (int r = 0; r < 4; ++r) {
        mx = fmaxf(mx, s0[nf][r]);
        mx = fmaxf(mx, s1[nf][r]);
      }
#pragma unroll
    for (int off = 1; off < 64; off <<= 1) mx = fmaxf(mx, __shfl_xor(mx, off));

    if (mx > m_w) {
      float sf = EXP2(m_w - mx);
      m_w = mx;
#pragma unroll
      for (int sub = 0; sub < 2; ++sub) {
#pragma unroll
        for (int df = 0; df < 4; ++df)
#pragma unroll
          for (int r = 0; r < 4; ++r) ctx[sub][df][r] *= sf;
#pragma unroll
        for (int r = 0; r < 4; ++r) lsum[sub][r] *= sf;
      }
    }

#pragma unroll
    for (int nf = 0; nf < 4; ++nf)
#pragma unroll
      for (int r = 0; r < 4; ++r) {
        Ps[wave][(0 * 16 + kg * 4 + r) * 40 + nf * 16 + lr] = (__bf16)EXP2(s0[nf][r] - m_w);
        Ps[wave][(1 * 16 + kg * 4 + r) * 40 + nf * 16 + lr] = (__bf16)EXP2(s1[nf][r] - m_w);
      }

    bf16x8 p00 = *reinterpret_cast<const bf16x8*>(&Ps[wave][(0 * 16 + lr) * 40 + kg * 8]);
    bf16x8 p01 = *reinterpret_cast<const bf16x8*>(&Ps[wave][(0 * 16 + lr) * 40 + 32 + kg * 8]);
    bf16x8 p10 = *reinterpret_cast<const bf16x8*>(&Ps[wave][(1 * 16 + lr) * 40 + kg * 8]);
    bf16x8 p11 = *reinterpret_cast<const bf16x8*>(&Ps[wave][(1 * 16 + lr) * 40 + 32 + kg * 8]);
    __builtin_amdgcn_s_setprio(1);
#pragma unroll
    for (int df = 0; df < 4; ++df) {
      int row = df * 16 + lr;
      bf16x8 vf0 = *reinterpret_cast<const bf16x8*>(&Vs[cur][row * 64 + ((kg * 8) ^ fswz)]);
      bf16x8 vf1 = *reinterpret_cast<const bf16x8*>(&Vs[cur][row * 64 + ((32 + kg * 8) ^ fswz)]);
      ctx[0][df] = __builtin_amdgcn_mfma_f32_16x16x32_bf16(p00, vf0, ctx[0][df], 0, 0, 0);
      ctx[0][df] = __builtin_amdgcn_mfma_f32_16x16x32_bf16(p01, vf1, ctx[0][df], 0, 0, 0);
      ctx[1][df] = __builtin_amdgcn_mfma_f32_16x16x32_bf16(p10, vf0, ctx[1][df], 0, 0, 0);
      ctx[1][df] = __builtin_amdgcn_mfma_f32_16x16x32_bf16(p11, vf1, ctx[1][df], 0, 0, 0);
    }
    lsum[0] = __builtin_amdgcn_mfma_f32_16x16x32_bf16(p00, ones, lsum[0], 0, 0, 0);
    lsum[0] = __builtin_amdgcn_mfma_f32_16x16x32_bf16(p01, ones, lsum[0], 0, 0, 0);
    lsum[1] = __builtin_amdgcn_mfma_f32_16x16x32_bf16(p10, ones, lsum[1], 0, 0, 0);
    lsum[1] = __builtin_amdgcn_mfma_f32_16x16x32_bf16(p11, ones, lsum[1], 0, 0, 0);
    __builtin_amdgcn_s_setprio(0);

    __syncthreads();
  }

#pragma unroll
  for (int sub = 0; sub < 2; ++sub)
#pragma unroll
    for (int r = 0; r < 4; ++r) {
      float rl = 1.0f / lsum[sub][r];
#pragma unroll
      for (int df = 0; df < 4; ++df) {
        float v = ctx[sub][df][r] * rl;
        O[(rowbase + q0 + sub * 16 + kg * 4 + r) * H_ + hcol + df * 16 + lr] = f2bf(v);
      }
    }
}

// ---------------- fused residual add + LayerNorm ----------------
template<int IN2_BF16, int WRITE_BF16>
__global__ __launch_bounds__(256) void add_ln(const float* __restrict__ X,
                                              const void* __restrict__ Y,
                                              const float* __restrict__ g,
                                              const float* __restrict__ beta,
                                              float* __restrict__ outF,
                                              unsigned short* __restrict__ outB) {
  const int row = blockIdx.x;
  const int tid = threadIdx.x;
  const int wave = tid >> 6, lane = tid & 63;
  __shared__ float red[8];

  float vals[4];
  float s = 0.0f, s2 = 0.0f;
#pragma unroll
  for (int i = 0; i < 4; ++i) {
    int c = i * 256 + tid;
    float v = X[(size_t)row * H_ + c];
    if (IN2_BF16) v += bf2f(reinterpret_cast<const unsigned short*>(Y)[(size_t)row * H_ + c]);
    else          v += reinterpret_cast<const float*>(Y)[(size_t)row * H_ + c];
    vals[i] = v;
    s += v;
    s2 += v * v;
  }
#pragma unroll
  for (int off = 32; off; off >>= 1) { s += __shfl_xor(s, off); s2 += __shfl_xor(s2, off); }
  if (lane == 0) { red[wave * 2] = s; red[wave * 2 + 1] = s2; }
  __syncthreads();
  s  = red[0] + red[2] + red[4] + red[6];
  s2 = red[1] + red[3] + red[5] + red[7];
  float mean = s * (1.0f / H_);
  float var  = s2 * (1.0f / H_) - mean * mean;
  float rstd = rsqrtf(var + 1e-5f);
#pragma unroll
  for (int i = 0; i < 4; ++i) {
    int c = i * 256 + tid;
    float v = (vals[i] - mean) * rstd * g[c] + beta[c];
    if (outF) outF[(size_t)row * H_ + c] = v;
    if (WRITE_BF16) outB[(size_t)row * H_ + c] = f2bf(v);
  }
}

// ---------------- orchestration ----------------
extern "C" void kernel_launch(void* const* d_in, const int* in_sizes, int n_in,
                              void* d_out, int out_size, void* d_ws, size_t ws_size,
                              hipStream_t stream) {
  const float* x  = (const float*)d_in[0];
  const float* Wq = (const float*)d_in[1];
  const float* bq = (const float*)d_in[2];
  const float* Wk = (const float*)d_in[3];
  const float* bk = (const float*)d_in[4];
  const float* Wv = (const float*)d_in[5];
  const float* bv = (const float*)d_in[6];
  const float* Wi = (const float*)d_in[7];
  const float* bi = (const float*)d_in[8];
  const float* Wo = (const float*)d_in[9];
  const float* bo = (const float*)d_in[10];
  const float* g1 = (const float*)d_in[11];
  const float* b1 = (const float*)d_in[12];
  const float* g2 = (const float*)d_in[13];
  const float* b2 = (const float*)d_in[14];

  unsigned char* ws = (unsigned char*)d_ws;
  size_t off = 0;
  auto alloc = [&](size_t bytes) { size_t o = off; off += (bytes + 255) & ~(size_t)255; return o; };

  unsigned short* xb    = (unsigned short*)(ws + alloc((size_t)M_ * H_ * 2));
  unsigned short* WqkvT = (unsigned short*)(ws + alloc((size_t)3 * H_ * H_ * 2));  // [3072][1024]
  unsigned short* WiT   = (unsigned short*)(ws + alloc((size_t)H_ * FF_ * 2));
  unsigned short* WoT   = (unsigned short*)(ws + alloc((size_t)FF_ * H_ * 2));
  unsigned short* qb    = (unsigned short*)(ws + alloc((size_t)M_ * H_ * 2));
  unsigned short* kb    = (unsigned short*)(ws + alloc((size_t)M_ * H_ * 2));
  unsigned short* vt    = (unsigned short*)(ws + alloc((size_t)M_ * H_ * 2));  // V^T [H][M]
  unsigned short* ao    = (unsigned short*)(ws + alloc((size_t)M_ * H_ * 2));
  float*          hf    = (float*)(ws + alloc((size_t)M_ * H_ * 4));
  unsigned short* hb    = (unsigned short*)(ws + alloc((size_t)M_ * H_ * 2));
  unsigned short* f1    = (unsigned short*)(ws + alloc((size_t)M_ * FF_ * 2));
  float*          f2    = (float*)(ws + alloc((size_t)M_ * H_ * 4));

  {
    int n4 = (int)((size_t)M_ * H_ / 4);
    cast_f32_bf16<<<(n4 + 255) / 256, 256, 0, stream>>>(x, xb, n4);
  }
  transpose_cast<<<dim3(H_ / 32, H_ / 32), 256, 0, stream>>>(Wq, WqkvT, H_, H_);
  transpose_cast<<<dim3(H_ / 32, H_ / 32), 256, 0, stream>>>(Wk, WqkvT + (size_t)H_ * H_, H_, H_);
  transpose_cast<<<dim3(H_ / 32, H_ / 32), 256, 0, stream>>>(Wv, WqkvT + (size_t)2 * H_ * H_, H_, H_);
  transpose_cast<<<dim3(FF_ / 32, H_ / 32), 256, 0, stream>>>(Wi, WiT, H_, FF_);
  transpose_cast<<<dim3(H_ / 32, FF_ / 32), 256, 0, stream>>>(Wo, WoT, FF_, H_);

  const float QSCALE = 0.125f * 1.44269504088896340736f;

  // fused QKV projection: [M,3072]
  gemm_qkv<<<dim3(M_ / 256, 3072 / 128), 512, 0, stream>>>(xb, WqkvT, bq, bk, bv,
                                                           qb, kb, vt, QSCALE);

  attn_fwd<<<dim3(S_ / 128, B_ * NH_), 256, 0, stream>>>(qb, kb, vt, ao);

  add_ln<1, 1><<<M_, 256, 0, stream>>>(x, ao, g1, b1, hf, hb);

  gemm_tn<1, 0><<<dim3(M_ / 256, FF_ / 128), 512, 0, stream>>>(hb, WiT, bi, f1, M_, FF_, H_);
  gemm_tn<0, 1><<<dim3(M_ / 256, H_ / 128), 512, 0, stream>>>(f1, WoT, bo, f2, M_, H_, FF_);

  add_ln<0, 0><<<M_, 256, 0, stream>>>(hf, f2, g2, b2, (float*)d_out, nullptr);
}